// Round 2
// baseline (2182.523 us; speedup 1.0000x reference)
//
#include <hip/hip_runtime.h>
#include <math.h>

#define NEG_INF (-3.402823466e+38f)

// ---- dims ----
constexpr int NTOK = 4608;              // 2560 Q + 768 Wp + 256 Rp + 768 Wr + 256 Rr
constexpr int BH = 64 * 256;            // 16384, one (b,u) plane

// ---- ws offsets (floats) ----
constexpr size_t OFF_WIHT = 0;                          // 300*2048
constexpr size_t OFF_WQ   = OFF_WIHT + 300*2048;        // 524288
constexpr size_t OFF_L2T  = OFF_WQ   + 524288;          // 262144
constexpr size_t OFF_B2   = OFF_L2T  + 262144;          // 2048
constexpr size_t OFF_XALL = OFF_B2   + 2048;            // 4608*300
constexpr size_t OFF_XP   = OFF_XALL + 1382400;         // 4608*2048 = 9437184
constexpr size_t OFF_HSQ  = OFF_XP   + 9437184;
constexpr size_t OFF_HSWP = OFF_HSQ  + 2*40*BH;
constexpr size_t OFF_HSRP = OFF_HSWP + 2*12*BH;
constexpr size_t OFF_HSWR = OFF_HSRP + 2*4*BH;
constexpr size_t OFF_HSRR = OFF_HSWR + 2*12*BH;
constexpr size_t OFF_CS   = OFF_HSRR + 2*4*BH;
constexpr size_t OFF_QO1  = OFF_CS   + 10*BH;           // 64*40*512
constexpr size_t OFF_RELP = OFF_QO1  + 1310720;
constexpr size_t OFF_RELC = OFF_RELP + 524288;
constexpr size_t OFF_RELW = OFF_RELC + 524288;
constexpr size_t OFF_EN   = OFF_RELW + 524288;          // 64*640
constexpr size_t OFF_ATT  = OFF_EN   + 40960;           // 64*40*512
constexpr size_t OFF_W1T  = OFF_ATT  + 1310720;         // 1024*192
constexpr size_t OFF_W2T  = OFF_W1T  + 196608;          // 3072*192
constexpr size_t OFF_W3T  = OFF_W2T  + 589824;          // 5120*192
// Dbuf, QO2, M2, Y1..Y3 alias the XP region (XP dead after last lstm step)

// ================= prep: weight transposes =================
__global__ __launch_bounds__(256) void k_prep(
    const float* __restrict__ Wih_f, const float* __restrict__ Wih_b,
    const float* __restrict__ Whh_f, const float* __restrict__ Whh_b,
    const float* __restrict__ b_f,   const float* __restrict__ b_b,
    const float* __restrict__ l2w,
    const float* __restrict__ c1w, const float* __restrict__ c2w, const float* __restrict__ c3w,
    float* __restrict__ WIHT, float* __restrict__ WQ,
    float* __restrict__ L2T,  float* __restrict__ B2,
    float* __restrict__ W1T,  float* __restrict__ W2T, float* __restrict__ W3T) {
  int idx = blockIdx.x * 256 + threadIdx.x;
  if (idx < 614400) {                       // WIHT[k][n], n = dir*1024 + j
    int n = idx & 2047, k = idx >> 11;
    WIHT[idx] = (n < 1024) ? Wih_f[(size_t)n*300 + k]
                           : Wih_b[(size_t)(n-1024)*300 + k];
    return;
  }
  idx -= 614400;
  if (idx < 524288) {                       // WQ[d][k4][g][u][kk]
    int d = idx >> 18, l = idx & 262143;
    int kk = l & 3, u = (l >> 2) & 255, g = (l >> 10) & 3, k4 = l >> 12;
    const float* Wh = d ? Whh_b : Whh_f;
    WQ[idx] = Wh[(size_t)(g*256 + u)*256 + k4*4 + kk];
    return;
  }
  idx -= 524288;
  if (idx < 262144) {                       // L2T[k][h] = l2w[h][k]
    int h = idx & 511, k = idx >> 9;
    L2T[idx] = l2w[(size_t)h*512 + k];
    return;
  }
  idx -= 262144;
  if (idx < 2048) { B2[idx] = (idx < 1024) ? b_f[idx] : b_b[idx-1024]; return; }
  idx -= 2048;
  if (idx < 196608) {                       // W1T[c][o] (o padded to 192)
    int o = idx % 192, c = idx / 192;
    W1T[idx] = (o < 150) ? c1w[(size_t)o*1024 + c] : 0.f;
    return;
  }
  idx -= 196608;
  if (idx < 589824) {                       // W2T[kk*1024+c][o]
    int o = idx % 192, j = idx / 192;
    int kk = j >> 10, c = j & 1023;
    W2T[idx] = (o < 150) ? c2w[((size_t)o*1024 + c)*3 + kk] : 0.f;
    return;
  }
  idx -= 589824;
  if (idx < 983040) {                       // W3T[kk*1024+c][o]
    int o = idx % 192, j = idx / 192;
    int kk = j >> 10, c = j & 1023;
    W3T[idx] = (o < 150) ? c3w[((size_t)o*1024 + c)*5 + kk] : 0.f;
  }
}

// ================= gather embeddings =================
__global__ __launch_bounds__(320) void k_gather(
    const int* __restrict__ q,  const int* __restrict__ wr, const int* __restrict__ rr,
    const int* __restrict__ wp, const int* __restrict__ rp,
    const float* __restrict__ we, const float* __restrict__ re,
    float* __restrict__ XALL) {
  int m = blockIdx.x, k = threadIdx.x;
  if (k >= 300) return;
  const float* emb; int row;
  if (m < 2560)      { int t=m>>6,    b=m&63; row = q [b*40+t]; emb = we; }
  else if (m < 3328) { int mm=m-2560; int t=mm>>6,b=mm&63; row = wp[b*12+t]; emb = we; }
  else if (m < 3584) { int mm=m-3328; int t=mm>>6,b=mm&63; row = rp[b*4 +t]; emb = re; }
  else if (m < 4352) { int mm=m-3584; int t=mm>>6,b=mm&63; row = wr[b*12+t]; emb = we; }
  else               { int mm=m-4352; int t=mm>>6,b=mm&63; row = rr[b*4 +t]; emb = re; }
  XALL[(size_t)m*300 + k] = emb[(size_t)row*300 + k];
}

// ===== generic tiled fp32 GEMM: C[M][N] = A[M x K, row stride lda] @ B[K][N] (+bias[N]) =====
template<bool BIAS>
__global__ __launch_bounds__(256) void k_gemm(
    const float* __restrict__ A, const float* __restrict__ Bm,
    const float* __restrict__ bias, float* __restrict__ C,
    int M, int N, int K, int lda) {
  __shared__ float As[16][68];
  __shared__ float Bs[16][68];
  int tid = threadIdx.x;
  int tx = tid & 15, ty = tid >> 4;
  int m0 = blockIdx.x << 6, n0 = blockIdx.y << 6;
  int mm = tid >> 2, kq = (tid & 3) << 2;
  int nn = tid & 63, kb = tid >> 6;
  float acc[4][4] = {};
  for (int k0 = 0; k0 < K; k0 += 16) {
    const float* ap = A + (size_t)(m0 + mm) * lda + k0 + kq;
    float4 av;
    if (k0 + kq + 3 < K) av = *(const float4*)ap;
    else {
      av.x = (k0+kq+0 < K) ? ap[0] : 0.f;
      av.y = (k0+kq+1 < K) ? ap[1] : 0.f;
      av.z = (k0+kq+2 < K) ? ap[2] : 0.f;
      av.w = (k0+kq+3 < K) ? ap[3] : 0.f;
    }
    As[kq+0][mm]=av.x; As[kq+1][mm]=av.y; As[kq+2][mm]=av.z; As[kq+3][mm]=av.w;
#pragma unroll
    for (int i = 0; i < 4; i++) {
      int kk = kb + (i << 2);
      Bs[kk][nn] = (k0 + kk < K) ? Bm[(size_t)(k0+kk)*N + n0 + nn] : 0.f;
    }
    __syncthreads();
#pragma unroll
    for (int kk = 0; kk < 16; kk++) {
      float4 a4 = *(const float4*)&As[kk][ty << 2];
      float4 b4 = *(const float4*)&Bs[kk][tx << 2];
      acc[0][0]+=a4.x*b4.x; acc[0][1]+=a4.x*b4.y; acc[0][2]+=a4.x*b4.z; acc[0][3]+=a4.x*b4.w;
      acc[1][0]+=a4.y*b4.x; acc[1][1]+=a4.y*b4.y; acc[1][2]+=a4.y*b4.z; acc[1][3]+=a4.y*b4.w;
      acc[2][0]+=a4.z*b4.x; acc[2][1]+=a4.z*b4.y; acc[2][2]+=a4.z*b4.z; acc[2][3]+=a4.z*b4.w;
      acc[3][0]+=a4.w*b4.x; acc[3][1]+=a4.w*b4.y; acc[3][2]+=a4.w*b4.z; acc[3][3]+=a4.w*b4.w;
    }
    __syncthreads();
  }
#pragma unroll
  for (int i = 0; i < 4; i++) {
    int row = m0 + (ty << 2) + i;
    float4 o4 = make_float4(acc[i][0], acc[i][1], acc[i][2], acc[i][3]);
    if (BIAS) {
      float4 bv = *(const float4*)(bias + n0 + (tx << 2));
      o4.x += bv.x; o4.y += bv.y; o4.z += bv.z; o4.w += bv.w;
    }
    *(float4*)(C + (size_t)row * N + n0 + (tx << 2)) = o4;
  }
}

// ================= one recurrent step, all active (seq,dir) slots =================
template<int BB>
__global__ __launch_bounds__(256) void k_step(
    const float* __restrict__ WQ, const float* __restrict__ XP,
    float* __restrict__ hsQ, float* __restrict__ hsWp, float* __restrict__ hsRp,
    float* __restrict__ hsWr, float* __restrict__ hsRr, float* __restrict__ CS,
    int step) {
  int slot = blockIdx.y;
  int dir = slot & 1, si = slot >> 1;
  int t, T, seg; float* hs; float* cs;
  const float* ih = nullptr; const float* ic = nullptr;
  if (si == 0) { t = step; T = 40; seg = 0; hs = hsQ; cs = CS + (size_t)(0 + dir) * BH; }
  else if (step < 12) {
    t = step; T = 12;
    if (si == 1) { seg = 2560; hs = hsWp; cs = CS + (size_t)(2 + dir) * BH; }
    else         { seg = 3584; hs = hsWr; cs = CS + (size_t)(6 + dir) * BH; }
  } else {
    t = step - 12; T = 4;
    if (si == 1) { seg = 3328; hs = hsRp; cs = CS + (size_t)(4 + dir) * BH;
                   ih = hsWp + (size_t)(dir*12 + 11) * BH; ic = CS + (size_t)(2 + dir) * BH; }
    else         { seg = 4352; hs = hsRr; cs = CS + (size_t)(8 + dir) * BH;
                   ih = hsWr + (size_t)(dir*12 + 11) * BH; ic = CS + (size_t)(6 + dir) * BH; }
  }
  hs += (size_t)dir * T * BH;
  int b0 = blockIdx.x * BB;
  int u = threadIdx.x;

  __shared__ float hl[BB][260];
  for (int i = threadIdx.x; i < BB * 256; i += 256) {
    int bb = i >> 8, uu = i & 255;
    float v;
    if (t == 0) v = ih ? ih[(b0 + bb) * 256 + uu] : 0.f;
    else        v = hs[(size_t)(t-1) * BH + (b0 + bb) * 256 + uu];
    hl[bb][uu] = v;
  }
  __syncthreads();

  float acc[4][BB];
#pragma unroll
  for (int g = 0; g < 4; g++)
#pragma unroll
    for (int b = 0; b < BB; b++) acc[g][b] = 0.f;

  const float* wb = WQ + (size_t)dir * 262144 + u * 4;
#pragma unroll 2
  for (int k4 = 0; k4 < 64; k4++) {
    float4 w0 = *(const float4*)(wb + k4*4096);
    float4 w1 = *(const float4*)(wb + k4*4096 + 1024);
    float4 w2 = *(const float4*)(wb + k4*4096 + 2048);
    float4 w3 = *(const float4*)(wb + k4*4096 + 3072);
#pragma unroll
    for (int b = 0; b < BB; b++) {
      float4 h4 = *(const float4*)&hl[b][k4*4];
      acc[0][b] += w0.x*h4.x + w0.y*h4.y + w0.z*h4.z + w0.w*h4.w;
      acc[1][b] += w1.x*h4.x + w1.y*h4.y + w1.z*h4.z + w1.w*h4.w;
      acc[2][b] += w2.x*h4.x + w2.y*h4.y + w2.z*h4.z + w2.w*h4.w;
      acc[3][b] += w3.x*h4.x + w3.y*h4.y + w3.z*h4.z + w3.w*h4.w;
    }
  }

  int t_in = dir ? (T - 1 - t) : t;
#pragma unroll
  for (int b = 0; b < BB; b++) {
    const float* xr = XP + (size_t)(seg + t_in*64 + b0 + b) * 2048 + dir*1024 + u;
    float zi = acc[0][b] + xr[0];
    float zf = acc[1][b] + xr[256];
    float zg = acc[2][b] + xr[512];
    float zo = acc[3][b] + xr[768];
    float cprev;
    if (t == 0) cprev = ic ? ic[(b0 + b) * 256 + u] : 0.f;
    else        cprev = cs[(b0 + b) * 256 + u];
    float gi = 1.f / (1.f + expf(-zi));
    float gf = 1.f / (1.f + expf(-zf));
    float go = 1.f / (1.f + expf(-zo));
    float gg = tanhf(zg);
    float cn = gf * cprev + gi * gg;
    float hn = go * tanhf(cn);
    cs[(b0 + b) * 256 + u] = cn;
    hs[(size_t)t * BH + (b0 + b) * 256 + u] = hn;
  }
}

// ================= question_out as [b][s][h] =================
__global__ __launch_bounds__(256) void k_qo1(const float* __restrict__ hsQ, float* __restrict__ QT) {
  int idx = blockIdx.x * 256 + threadIdx.x;
  if (idx >= 64*40*512) return;
  int h = idx & 511; int t2 = idx >> 9; int s = t2 % 40; int b = t2 / 40;
  float v;
  if (h < 256) v = hsQ[(size_t)s * BH + b*256 + h];
  else         v = hsQ[(size_t)40 * BH + (size_t)(39 - s) * BH + b*256 + (h - 256)];
  QT[idx] = v;
}

// ================= relation tensors [b][r][h], both calls =================
__global__ __launch_bounds__(256) void k_rel(
    const float* __restrict__ hsWp, const float* __restrict__ hsRp,
    const float* __restrict__ hsWr, const float* __restrict__ hsRr,
    float* __restrict__ RELP, float* __restrict__ RELC) {
  int idx0 = blockIdx.x * 256 + threadIdx.x;
  if (idx0 >= 2*64*16*512) return;
  int call = idx0 >= 64*16*512;
  int idx = idx0 - call * 64*16*512;
  int h = idx & 511; int t2 = idx >> 9; int r = t2 & 15; int b = t2 >> 4;
  const float* hsW = call ? hsWr : hsWp;
  const float* hsR = call ? hsRr : hsRp;
  float v;
  if (r < 4) {
    if (h < 256) v = hsR[(size_t)r * BH + b*256 + h];
    else         v = hsR[(size_t)4 * BH + (size_t)(3 - r) * BH + b*256 + (h - 256)];
  } else {
    int t = r - 4;
    if (h < 256) v = hsW[(size_t)t * BH + b*256 + h];
    else         v = hsW[(size_t)12 * BH + (size_t)(11 - t) * BH + b*256 + (h - 256)];
  }
  (call ? RELC : RELP)[idx] = v;
}

// ================= energy[b][r][s] =================
__global__ __launch_bounds__(256) void k_energy(
    const float* __restrict__ relW, const float* __restrict__ QT, float* __restrict__ EN) {
  int idx = blockIdx.x * 256 + threadIdx.x;
  if (idx >= 64*16*40) return;
  int s = idx % 40; int t = idx / 40; int r = t & 15; int b = t >> 4;
  const float* rw = relW + (size_t)(b*16 + r) * 512;
  const float* qv = QT   + (size_t)(b*40 + s) * 512;
  float acc = 0.f;
#pragma unroll 4
  for (int k = 0; k < 512; k += 4) {
    float4 a = *(const float4*)(rw + k);
    float4 c = *(const float4*)(qv + k);
    acc += a.x*c.x + a.y*c.y + a.z*c.z + a.w*c.w;
  }
  EN[idx] = acc;
}

// ================= softmax over 640 per b =================
__global__ __launch_bounds__(256) void k_softmax(float* __restrict__ EN) {
  int b = blockIdx.x; int tid = threadIdx.x;
  float* e = EN + b * 640;
  float v0 = e[tid] * 0.25f, v1 = e[tid + 256] * 0.25f;
  float v2 = (tid < 128) ? e[tid + 512] * 0.25f : NEG_INF;
  __shared__ float sh[256];
  sh[tid] = fmaxf(v0, fmaxf(v1, v2));
  __syncthreads();
  for (int st = 128; st > 0; st >>= 1) { if (tid < st) sh[tid] = fmaxf(sh[tid], sh[tid+st]); __syncthreads(); }
  float m = sh[0];
  __syncthreads();
  float e0 = expf(v0 - m), e1 = expf(v1 - m);
  float e2 = (tid < 128) ? expf(v2 - m) : 0.f;
  sh[tid] = e0 + e1 + e2;
  __syncthreads();
  for (int st = 128; st > 0; st >>= 1) { if (tid < st) sh[tid] += sh[tid+st]; __syncthreads(); }
  float inv = 1.f / sh[0];
  e[tid] = e0 * inv; e[tid + 256] = e1 * inv;
  if (tid < 128) e[tid + 512] = e2 * inv;
}

// ================= atten[b][s][h] =================
__global__ __launch_bounds__(256) void k_atten(
    const float* __restrict__ AL, const float* __restrict__ REL, float* __restrict__ ATT) {
  int idx = blockIdx.x * 256 + threadIdx.x;
  if (idx >= 64*40*512) return;
  int h = idx & 511; int t2 = idx >> 9; int s = t2 % 40; int b = t2 / 40;
  const float* al = AL + b * 640 + s;
  const float* rl = REL + (size_t)b * 16 * 512 + h;
  float acc = 0.f;
#pragma unroll
  for (int r = 0; r < 16; r++) acc += al[r*40] * rl[r*512];
  ATT[idx] = acc;
}

__global__ __launch_bounds__(256) void k_sub(
    const float* __restrict__ QT, const float* __restrict__ ATT, float* __restrict__ D) {
  int idx = blockIdx.x * 256 + threadIdx.x;
  if (idx < 64*40*512) D[idx] = QT[idx] - ATT[idx];
}

// ================= pack M2[m=b*40+l][c(1024)] (coalesced concat) =================
__global__ __launch_bounds__(256) void k_m2(
    const float* __restrict__ QO2, const float* __restrict__ ATT, float* __restrict__ M2) {
  int idx = blockIdx.x * 256 + threadIdx.x;
  if (idx >= 2621440) return;
  int c = idx & 1023; int m = idx >> 10;
  M2[idx] = (c < 512) ? QO2[(size_t)m*512 + c] : ATT[(size_t)m*512 + (c - 512)];
}

// ================= pool(bias+relu+max over l) + score, one block per b =================
__global__ __launch_bounds__(256) void k_pool(
    const float* __restrict__ Y1, const float* __restrict__ Y2, const float* __restrict__ Y3,
    const float* __restrict__ b1, const float* __restrict__ b2, const float* __restrict__ b3,
    const float* __restrict__ lw, float* __restrict__ out) {
  int b = blockIdx.x, o = threadIdx.x;
  float hv = 0.f;
  if (o < 150) {
    const float* y1 = Y1 + (size_t)b*40*192 + o;
    const float* y2 = Y2 + (size_t)b*40*192 + o;
    const float* y3 = Y3 + (size_t)b*40*192 + o;
    float m1 = NEG_INF, m2 = NEG_INF, m3 = NEG_INF;
#pragma unroll 4
    for (int l = 0; l < 40; l++) m1 = fmaxf(m1, y1[l*192]);
#pragma unroll 2
    for (int l = 0; l < 38; l++) m2 = fmaxf(m2, y2[l*192]);
#pragma unroll 2
    for (int l = 0; l < 36; l++) m3 = fmaxf(m3, y3[l*192]);
    float h = fmaxf(fmaxf(m1 + b1[o], m2 + b2[o]), m3 + b3[o]);
    hv = fmaxf(h, 0.f) * lw[o];
  }
  __shared__ float sh[256];
  sh[threadIdx.x] = hv;
  __syncthreads();
  for (int st = 128; st > 0; st >>= 1) { if (threadIdx.x < st) sh[threadIdx.x] += sh[threadIdx.x+st]; __syncthreads(); }
  if (threadIdx.x == 0) out[b] = sh[0];
}

// ================= host =================
extern "C" void kernel_launch(void* const* d_in, const int* in_sizes, int n_in,
                              void* d_out, int out_size, void* d_ws, size_t ws_size,
                              hipStream_t stream) {
  const int*   q    = (const int*)d_in[0];
  const int*   wrel = (const int*)d_in[1];
  const int*   rrel = (const int*)d_in[2];
  const int*   wprv = (const int*)d_in[3];
  const int*   rprv = (const int*)d_in[4];
  const float* we   = (const float*)d_in[5];
  const float* re   = (const float*)d_in[6];
  const float* Wih_f= (const float*)d_in[7];
  const float* Whh_f= (const float*)d_in[8];
  const float* b_f  = (const float*)d_in[9];
  const float* Wih_b= (const float*)d_in[10];
  const float* Whh_b= (const float*)d_in[11];
  const float* b_b  = (const float*)d_in[12];
  const float* W    = (const float*)d_in[13];
  const float* c1w  = (const float*)d_in[14];
  const float* c1b  = (const float*)d_in[15];
  const float* c2w  = (const float*)d_in[16];
  const float* c2b  = (const float*)d_in[17];
  const float* c3w  = (const float*)d_in[18];
  const float* c3b  = (const float*)d_in[19];
  const float* lw   = (const float*)d_in[20];
  const float* l2w  = (const float*)d_in[21];
  const float* l2b  = (const float*)d_in[22];
  float* out = (float*)d_out;
  float* ws  = (float*)d_ws;

  float* WIHT = ws + OFF_WIHT;
  float* WQk  = ws + OFF_WQ;
  float* L2T  = ws + OFF_L2T;
  float* B2   = ws + OFF_B2;
  float* XALL = ws + OFF_XALL;
  float* XP   = ws + OFF_XP;
  float* HSQ  = ws + OFF_HSQ;
  float* HSWP = ws + OFF_HSWP;
  float* HSRP = ws + OFF_HSRP;
  float* HSWR = ws + OFF_HSWR;
  float* HSRR = ws + OFF_HSRR;
  float* CS   = ws + OFF_CS;
  float* QO1  = ws + OFF_QO1;
  float* RELP = ws + OFF_RELP;
  float* RELC = ws + OFF_RELC;
  float* RELW = ws + OFF_RELW;
  float* EN   = ws + OFF_EN;
  float* ATT  = ws + OFF_ATT;
  float* W1T  = ws + OFF_W1T;
  float* W2T  = ws + OFF_W2T;
  float* W3T  = ws + OFF_W3T;
  // aliases into dead XP region (XP = 9437184 floats)
  float* Dbuf = XP;                 // 1310720
  float* QO2  = XP + 1310720;       // 1310720
  float* M2   = XP + 2621440;       // 2621440
  float* Y1   = XP + 5242880;       // 491520
  float* Y2   = XP + 5734400;       // 491520
  float* Y3   = XP + 6225920;       // 491520

  k_prep<<<12392, 256, 0, stream>>>(Wih_f, Wih_b, Whh_f, Whh_b, b_f, b_b, l2w,
                                    c1w, c2w, c3w,
                                    WIHT, WQk, L2T, B2, W1T, W2T, W3T);
  k_gather<<<NTOK, 320, 0, stream>>>(q, wrel, rrel, wprv, rprv, we, re, XALL);
  { dim3 g(72, 32); k_gemm<true><<<g, 256, 0, stream>>>(XALL, WIHT, B2, XP, NTOK, 2048, 300, 300); }

  for (int s = 0; s < 40; s++) {
    if (s < 16) { dim3 g(16, 6); k_step<4><<<g, 256, 0, stream>>>(WQk, XP, HSQ, HSWP, HSRP, HSWR, HSRR, CS, s); }
    else        { dim3 g(32, 2); k_step<2><<<g, 256, 0, stream>>>(WQk, XP, HSQ, HSWP, HSRP, HSWR, HSRR, CS, s); }
  }

  k_qo1<<<5120, 256, 0, stream>>>(HSQ, QO1);
  k_rel<<<4096, 256, 0, stream>>>(HSWP, HSRP, HSWR, HSRR, RELP, RELC);

  // ---- attention (previous hop) ----
  { dim3 g(16, 8); k_gemm<false><<<g, 256, 0, stream>>>(RELP, W, nullptr, RELW, 1024, 512, 512, 512); }
  k_energy<<<160, 256, 0, stream>>>(RELW, QO1, EN);
  k_softmax<<<64, 256, 0, stream>>>(EN);
  k_atten<<<5120, 256, 0, stream>>>(EN, RELP, ATT);
  k_sub<<<5120, 256, 0, stream>>>(QO1, ATT, Dbuf);
  { dim3 g(40, 8); k_gemm<true><<<g, 256, 0, stream>>>(Dbuf, L2T, l2b, QO2, 2560, 512, 512, 512); }

  // ---- attention (current relation) ----
  { dim3 g(16, 8); k_gemm<false><<<g, 256, 0, stream>>>(RELC, W, nullptr, RELW, 1024, 512, 512, 512); }
  k_energy<<<160, 256, 0, stream>>>(RELW, QO2, EN);
  k_softmax<<<64, 256, 0, stream>>>(EN);
  k_atten<<<5120, 256, 0, stream>>>(EN, RELC, ATT);

  // ---- convs as GEMMs (M2 row stride 1024; K-window slides over adjacent l rows) ----
  k_m2<<<10240, 256, 0, stream>>>(QO2, ATT, M2);
  { dim3 g(40, 3); k_gemm<false><<<g, 256, 0, stream>>>(M2, W1T, nullptr, Y1, 2560, 192, 1024, 1024); }
  { dim3 g(40, 3); k_gemm<false><<<g, 256, 0, stream>>>(M2, W2T, nullptr, Y2, 2560, 192, 3072, 1024); }
  { dim3 g(40, 3); k_gemm<false><<<g, 256, 0, stream>>>(M2, W3T, nullptr, Y3, 2560, 192, 5120, 1024); }
  k_pool<<<64, 256, 0, stream>>>(Y1, Y2, Y3, c1b, c2b, c3b, lw, out);
}

// Round 3
// 1349.247 us; speedup vs baseline: 1.6176x; 1.6176x over previous
//
#include <hip/hip_runtime.h>
#include <math.h>

#define NEG_INF (-3.402823466e+38f)

typedef __attribute__((ext_vector_type(8))) short short8;
typedef __attribute__((ext_vector_type(8))) unsigned short ushort8;
typedef __attribute__((ext_vector_type(4))) float f32x4;

// ---- dims ----
constexpr int NTOK = 4608;              // 2560 Q + 768 Wp + 256 Rp + 768 Wr + 256 Rr
constexpr int BH = 64 * 256;            // one (b,u) plane

// ---- ws offsets (floats); ushort arrays use 2 elems per float slot ----
constexpr size_t OFF_WQ    = 0;                          // 524288
constexpr size_t OFF_B2    = OFF_WQ    + 524288;         // 2048
constexpr size_t OFF_XB3T  = OFF_B2    + 2048;           // 2048*960 us  = 983040 fl
constexpr size_t OFF_WB3T  = OFF_XB3T  + 983040;         // 512*1536 us  = 393216 fl
constexpr size_t OFF_L2B3T = OFF_WB3T  + 393216;         // 393216 fl
constexpr size_t OFF_C1B3T = OFF_L2B3T + 393216;         // 192*3072 us  = 294912 fl
constexpr size_t OFF_C2B3T = OFF_C1B3T + 294912;         // 192*9216 us  = 884736 fl
constexpr size_t OFF_C3B3T = OFF_C2B3T + 884736;         // 192*15360 us = 1474560 fl
constexpr size_t OFF_XHI   = OFF_C3B3T + 1474560;        // 4608*320 us  = 737280 fl
constexpr size_t OFF_XLO   = OFF_XHI   + 737280;
constexpr size_t OFF_XP    = OFF_XLO   + 737280;         // 4608*2048 fp32 = 9437184
constexpr size_t OFF_HSQ   = OFF_XP    + 9437184;        // 1310720
constexpr size_t OFF_HSWP  = OFF_HSQ   + 1310720;        // 393216
constexpr size_t OFF_HSRP  = OFF_HSWP  + 393216;         // 131072
constexpr size_t OFF_HSWR  = OFF_HSRP  + 131072;         // 393216
constexpr size_t OFF_HSRR  = OFF_HSWR  + 393216;         // 131072
constexpr size_t OFF_CS    = OFF_HSRR  + 131072;         // 163840
constexpr size_t OFF_RELP  = OFF_CS    + 163840;         // 524288
constexpr size_t OFF_RELC  = OFF_RELP  + 524288;         // 524288
constexpr size_t OFF_RELW  = OFF_RELC  + 524288;         // 524288
constexpr size_t OFF_EN    = OFF_RELW  + 524288;         // 40960
// end = OFF_EN + 40960 = 19998720 floats (~80 MB)
// XP region aliases (XP dead after last k_step):
//   QO1 +0 (1310720), ATT +1310720, QO2 +2621440,
//   Dhi +3932160 (655360 fl), Dlo +4587520,
//   RPhi +5242880, RPlo +5505024, RChi +5767168, RClo +6029312 (dead before k_m2)
//   M2hi +5242880 (1313024 fl), M2lo +6555904,
//   Y1 +7868928, Y2 +8360448, Y3 +8851968 (end 9343488 < 9437184)

__device__ inline unsigned short f2bf(float f) {
  unsigned int u = __float_as_uint(f);
  u += 0x7FFFu + ((u >> 16) & 1u);          // RNE
  return (unsigned short)(u >> 16);
}
__device__ inline float bf2f(unsigned short h) {
  return __uint_as_float(((unsigned int)h) << 16);
}

// ================= prep: WQ + bias + all B3T (bf16-split, transposed, [hi|lo|hi]) ==========
__global__ __launch_bounds__(256) void k_prep(
    const float* __restrict__ Whh_f, const float* __restrict__ Whh_b,
    const float* __restrict__ b_f,   const float* __restrict__ b_b,
    const float* __restrict__ Wih_f, const float* __restrict__ Wih_b,
    const float* __restrict__ Wat,   const float* __restrict__ l2w,
    const float* __restrict__ c1w, const float* __restrict__ c2w, const float* __restrict__ c3w,
    float* __restrict__ WQ, float* __restrict__ B2,
    unsigned short* __restrict__ XB3T, unsigned short* __restrict__ WB3T,
    unsigned short* __restrict__ L2B3T,
    unsigned short* __restrict__ C1B3T, unsigned short* __restrict__ C2B3T,
    unsigned short* __restrict__ C3B3T) {
  int idx = blockIdx.x * 256 + threadIdx.x;
  if (idx < 524288) {                       // WQ[d][k4][g][u][kk]
    int d = idx >> 18, l = idx & 262143;
    int kk = l & 3, u = (l >> 2) & 255, g = (l >> 10) & 3, k4 = l >> 12;
    const float* Wh = d ? Whh_b : Whh_f;
    WQ[idx] = Wh[(size_t)(g*256 + u)*256 + k4*4 + kk];
    return;
  }
  idx -= 524288;
  if (idx < 2048) { B2[idx] = (idx < 1024) ? b_f[idx] : b_b[idx-1024]; return; }
  idx -= 2048;
  unsigned short* dst; int n, k, K;
  float w;
  if (idx < 655360) {                       // XB3T: n<2048, Kp=320 (src K=300)
    n = idx / 320; k = idx % 320; K = 320; dst = XB3T;
    w = (k < 300) ? ((n < 1024) ? Wih_f[(size_t)n*300 + k] : Wih_b[(size_t)(n-1024)*300 + k]) : 0.f;
  } else if ((idx -= 655360) < 262144) {    // WB3T: B[k][n] = Wat[k][n]
    n = idx >> 9; k = idx & 511; K = 512; dst = WB3T;
    w = Wat[(size_t)k*512 + n];
  } else if ((idx -= 262144) < 262144) {    // L2B3T: B[k][n] = l2w[n][k]
    n = idx >> 9; k = idx & 511; K = 512; dst = L2B3T;
    w = l2w[(size_t)n*512 + k];
  } else if ((idx -= 262144) < 196608) {    // C1B3T (n pad 192)
    n = idx >> 10; k = idx & 1023; K = 1024; dst = C1B3T;
    w = (n < 150) ? c1w[(size_t)n*1024 + k] : 0.f;
  } else if ((idx -= 196608) < 589824) {    // C2B3T
    n = idx / 3072; k = idx % 3072; K = 3072; dst = C2B3T;
    int kw = k >> 10, c = k & 1023;
    w = (n < 150) ? c2w[((size_t)n*1024 + c)*3 + kw] : 0.f;
  } else if ((idx -= 589824) < 983040) {    // C3B3T
    n = idx / 5120; k = idx % 5120; K = 5120; dst = C3B3T;
    int kw = k >> 10, c = k & 1023;
    w = (n < 150) ? c3w[((size_t)n*1024 + c)*5 + kw] : 0.f;
  } else return;
  unsigned short hi = f2bf(w);
  unsigned short lo = f2bf(w - bf2f(hi));
  size_t base = (size_t)n * (3*K);
  dst[base + k] = hi;
  dst[base + K + k] = lo;
  dst[base + 2*K + k] = hi;
}

// ================= gather embeddings -> bf16 split, K padded to 320 =================
__global__ __launch_bounds__(320) void k_gather(
    const int* __restrict__ q,  const int* __restrict__ wr, const int* __restrict__ rr,
    const int* __restrict__ wp, const int* __restrict__ rp,
    const float* __restrict__ we, const float* __restrict__ re,
    unsigned short* __restrict__ Xhi, unsigned short* __restrict__ Xlo) {
  int m = blockIdx.x, k = threadIdx.x;
  const float* emb; int row;
  if (m < 2560)      { int t=m>>6,    b=m&63; row = q [b*40+t]; emb = we; }
  else if (m < 3328) { int mm=m-2560; int t=mm>>6,b=mm&63; row = wp[b*12+t]; emb = we; }
  else if (m < 3584) { int mm=m-3328; int t=mm>>6,b=mm&63; row = rp[b*4 +t]; emb = re; }
  else if (m < 4352) { int mm=m-3584; int t=mm>>6,b=mm&63; row = wr[b*12+t]; emb = we; }
  else               { int mm=m-4352; int t=mm>>6,b=mm&63; row = rr[b*4 +t]; emb = re; }
  float v = (k < 300) ? emb[(size_t)row*300 + k] : 0.f;
  unsigned short hi = f2bf(v);
  Xhi[(size_t)m*320 + k] = hi;
  Xlo[(size_t)m*320 + k] = f2bf(v - bf2f(hi));
}

// ===== MFMA GEMM (bf16 3-split): C[M][N] = sum over 3K of Asel[m][kk] * Bt[n][k0] =====
// A chunks: [hi, hi, lo] from Ahi/Alo (lda row stride, flat window ok);
// Bt[n][3K] pre-packed [hi|lo|hi]. Tile 64x64, 4 waves, 16x16x32 bf16 MFMA.
template<bool BIAS>
__global__ __launch_bounds__(256) void k_mgemm(
    const unsigned short* __restrict__ Ahi, const unsigned short* __restrict__ Alo, int lda,
    const unsigned short* __restrict__ Bt, const float* __restrict__ bias,
    float* __restrict__ C, int N, int K) {
  __shared__ unsigned short As[64 * 40];   // rows padded to 40 ushorts (80 B)
  __shared__ unsigned short Bs[64 * 40];
  int tid = threadIdx.x;
  int wave = tid >> 6, lane = tid & 63;
  int quad = lane >> 4, l16 = lane & 15;
  int m0 = blockIdx.x << 6, n0 = blockIdx.y << 6;
  int K3 = 3 * K;
  int sr = tid >> 2;               // staging row 0..63
  int sc = (tid & 3) << 3;         // staging col 0,8,16,24
  f32x4 acc[4] = {};
  for (int k0 = 0; k0 < K3; k0 += 32) {
    int c = (k0 >= K) + (k0 >= 2*K);
    const unsigned short* Asrc = (c == 2) ? Alo : Ahi;
    int kk = k0 - c * K;
    ushort8 av = *(const ushort8*)(Asrc + (size_t)(m0 + sr) * lda + kk + sc);
    ushort8 bv = *(const ushort8*)(Bt + (size_t)(n0 + sr) * K3 + k0 + sc);
    *(ushort8*)&As[sr * 40 + sc] = av;
    *(ushort8*)&Bs[sr * 40 + sc] = bv;
    __syncthreads();
    short8 a  = *(const short8*)&As[(wave*16 + l16) * 40 + quad*8];
    short8 b0 = *(const short8*)&Bs[( 0 + l16) * 40 + quad*8];
    short8 b1 = *(const short8*)&Bs[(16 + l16) * 40 + quad*8];
    short8 b2 = *(const short8*)&Bs[(32 + l16) * 40 + quad*8];
    short8 b3 = *(const short8*)&Bs[(48 + l16) * 40 + quad*8];
    acc[0] = __builtin_amdgcn_mfma_f32_16x16x32_bf16(a, b0, acc[0], 0, 0, 0);
    acc[1] = __builtin_amdgcn_mfma_f32_16x16x32_bf16(a, b1, acc[1], 0, 0, 0);
    acc[2] = __builtin_amdgcn_mfma_f32_16x16x32_bf16(a, b2, acc[2], 0, 0, 0);
    acc[3] = __builtin_amdgcn_mfma_f32_16x16x32_bf16(a, b3, acc[3], 0, 0, 0);
    __syncthreads();
  }
  int row0 = m0 + wave * 16 + quad * 4;    // C/D: col=lane&15, row=quad*4+reg (m89-verified)
#pragma unroll
  for (int t = 0; t < 4; t++) {
    int col = n0 + t * 16 + l16;
    float bb = BIAS ? bias[col] : 0.f;
#pragma unroll
    for (int r = 0; r < 4; r++)
      C[(size_t)(row0 + r) * N + col] = acc[t][r] + bb;
  }
}

// ================= one recurrent step, all active (seq,dir) slots =================
template<int BB>
__global__ __launch_bounds__(256) void k_step(
    const float* __restrict__ WQ, const float* __restrict__ XP,
    float* __restrict__ hsQ, float* __restrict__ hsWp, float* __restrict__ hsRp,
    float* __restrict__ hsWr, float* __restrict__ hsRr, float* __restrict__ CS,
    int step) {
  int slot = blockIdx.y;
  int dir = slot & 1, si = slot >> 1;
  int t, T, seg; float* hs; float* cs;
  const float* ih = nullptr; const float* ic = nullptr;
  if (si == 0) { t = step; T = 40; seg = 0; hs = hsQ; cs = CS + (size_t)(0 + dir) * BH; }
  else if (step < 12) {
    t = step; T = 12;
    if (si == 1) { seg = 2560; hs = hsWp; cs = CS + (size_t)(2 + dir) * BH; }
    else         { seg = 3584; hs = hsWr; cs = CS + (size_t)(6 + dir) * BH; }
  } else {
    t = step - 12; T = 4;
    if (si == 1) { seg = 3328; hs = hsRp; cs = CS + (size_t)(4 + dir) * BH;
                   ih = hsWp + (size_t)(dir*12 + 11) * BH; ic = CS + (size_t)(2 + dir) * BH; }
    else         { seg = 4352; hs = hsRr; cs = CS + (size_t)(8 + dir) * BH;
                   ih = hsWr + (size_t)(dir*12 + 11) * BH; ic = CS + (size_t)(6 + dir) * BH; }
  }
  hs += (size_t)dir * T * BH;
  int b0 = blockIdx.x * BB;
  int u = threadIdx.x;

  __shared__ float hl[BB][260];
  for (int i = threadIdx.x; i < BB * 256; i += 256) {
    int bb = i >> 8, uu = i & 255;
    float v;
    if (t == 0) v = ih ? ih[(b0 + bb) * 256 + uu] : 0.f;
    else        v = hs[(size_t)(t-1) * BH + (b0 + bb) * 256 + uu];
    hl[bb][uu] = v;
  }
  __syncthreads();

  float acc[4][BB];
#pragma unroll
  for (int g = 0; g < 4; g++)
#pragma unroll
    for (int b = 0; b < BB; b++) acc[g][b] = 0.f;

  const float* wb = WQ + (size_t)dir * 262144 + u * 4;
#pragma unroll 2
  for (int k4 = 0; k4 < 64; k4++) {
    float4 w0 = *(const float4*)(wb + k4*4096);
    float4 w1 = *(const float4*)(wb + k4*4096 + 1024);
    float4 w2 = *(const float4*)(wb + k4*4096 + 2048);
    float4 w3 = *(const float4*)(wb + k4*4096 + 3072);
#pragma unroll
    for (int b = 0; b < BB; b++) {
      float4 h4 = *(const float4*)&hl[b][k4*4];
      acc[0][b] += w0.x*h4.x + w0.y*h4.y + w0.z*h4.z + w0.w*h4.w;
      acc[1][b] += w1.x*h4.x + w1.y*h4.y + w1.z*h4.z + w1.w*h4.w;
      acc[2][b] += w2.x*h4.x + w2.y*h4.y + w2.z*h4.z + w2.w*h4.w;
      acc[3][b] += w3.x*h4.x + w3.y*h4.y + w3.z*h4.z + w3.w*h4.w;
    }
  }

  int t_in = dir ? (T - 1 - t) : t;
#pragma unroll
  for (int b = 0; b < BB; b++) {
    const float* xr = XP + (size_t)(seg + t_in*64 + b0 + b) * 2048 + dir*1024 + u;
    float zi = acc[0][b] + xr[0];
    float zf = acc[1][b] + xr[256];
    float zg = acc[2][b] + xr[512];
    float zo = acc[3][b] + xr[768];
    float cprev;
    if (t == 0) cprev = ic ? ic[(b0 + b) * 256 + u] : 0.f;
    else        cprev = cs[(b0 + b) * 256 + u];
    float gi = 1.f / (1.f + expf(-zi));
    float gf = 1.f / (1.f + expf(-zf));
    float go = 1.f / (1.f + expf(-zo));
    float gg = tanhf(zg);
    float cn = gf * cprev + gi * gg;
    float hn = go * tanhf(cn);
    cs[(b0 + b) * 256 + u] = cn;
    hs[(size_t)t * BH + (b0 + b) * 256 + u] = hn;
  }
}

// ================= question_out as [b][s][h] =================
__global__ __launch_bounds__(256) void k_qo1(const float* __restrict__ hsQ, float* __restrict__ QT) {
  int idx = blockIdx.x * 256 + threadIdx.x;
  if (idx >= 64*40*512) return;
  int h = idx & 511; int t2 = idx >> 9; int s = t2 % 40; int b = t2 / 40;
  float v;
  if (h < 256) v = hsQ[(size_t)s * BH + b*256 + h];
  else         v = hsQ[(size_t)40 * BH + (size_t)(39 - s) * BH + b*256 + (h - 256)];
  QT[idx] = v;
}

// ================= relation tensors [b][r][h] fp32 + bf16-split, both calls ==============
__global__ __launch_bounds__(256) void k_rel(
    const float* __restrict__ hsWp, const float* __restrict__ hsRp,
    const float* __restrict__ hsWr, const float* __restrict__ hsRr,
    float* __restrict__ RELP, float* __restrict__ RELC,
    unsigned short* __restrict__ RPhi, unsigned short* __restrict__ RPlo,
    unsigned short* __restrict__ RChi, unsigned short* __restrict__ RClo) {
  int idx0 = blockIdx.x * 256 + threadIdx.x;
  if (idx0 >= 2*64*16*512) return;
  int call = idx0 >= 64*16*512;
  int idx = idx0 - call * 64*16*512;
  int h = idx & 511; int t2 = idx >> 9; int r = t2 & 15; int b = t2 >> 4;
  const float* hsW = call ? hsWr : hsWp;
  const float* hsR = call ? hsRr : hsRp;
  float v;
  if (r < 4) {
    if (h < 256) v = hsR[(size_t)r * BH + b*256 + h];
    else         v = hsR[(size_t)4 * BH + (size_t)(3 - r) * BH + b*256 + (h - 256)];
  } else {
    int t = r - 4;
    if (h < 256) v = hsW[(size_t)t * BH + b*256 + h];
    else         v = hsW[(size_t)12 * BH + (size_t)(11 - t) * BH + b*256 + (h - 256)];
  }
  unsigned short hi = f2bf(v);
  unsigned short lo = f2bf(v - bf2f(hi));
  if (call) { RELC[idx] = v; RChi[idx] = hi; RClo[idx] = lo; }
  else      { RELP[idx] = v; RPhi[idx] = hi; RPlo[idx] = lo; }
}

// ================= energy[b][r][s] =================
__global__ __launch_bounds__(256) void k_energy(
    const float* __restrict__ relW, const float* __restrict__ QT, float* __restrict__ EN) {
  int idx = blockIdx.x * 256 + threadIdx.x;
  if (idx >= 64*16*40) return;
  int s = idx % 40; int t = idx / 40; int r = t & 15; int b = t >> 4;
  const float* rw = relW + (size_t)(b*16 + r) * 512;
  const float* qv = QT   + (size_t)(b*40 + s) * 512;
  float acc = 0.f;
#pragma unroll 4
  for (int k = 0; k < 512; k += 4) {
    float4 a = *(const float4*)(rw + k);
    float4 c = *(const float4*)(qv + k);
    acc += a.x*c.x + a.y*c.y + a.z*c.z + a.w*c.w;
  }
  EN[idx] = acc;
}

// ================= softmax over 640 per b =================
__global__ __launch_bounds__(256) void k_softmax(float* __restrict__ EN) {
  int b = blockIdx.x; int tid = threadIdx.x;
  float* e = EN + b * 640;
  float v0 = e[tid] * 0.25f, v1 = e[tid + 256] * 0.25f;
  float v2 = (tid < 128) ? e[tid + 512] * 0.25f : NEG_INF;
  __shared__ float sh[256];
  sh[tid] = fmaxf(v0, fmaxf(v1, v2));
  __syncthreads();
  for (int st = 128; st > 0; st >>= 1) { if (tid < st) sh[tid] = fmaxf(sh[tid], sh[tid+st]); __syncthreads(); }
  float m = sh[0];
  __syncthreads();
  float e0 = expf(v0 - m), e1 = expf(v1 - m);
  float e2 = (tid < 128) ? expf(v2 - m) : 0.f;
  sh[tid] = e0 + e1 + e2;
  __syncthreads();
  for (int st = 128; st > 0; st >>= 1) { if (tid < st) sh[tid] += sh[tid+st]; __syncthreads(); }
  float inv = 1.f / sh[0];
  e[tid] = e0 * inv; e[tid + 256] = e1 * inv;
  if (tid < 128) e[tid + 512] = e2 * inv;
}

// ================= atten[b][s][h] =================
__global__ __launch_bounds__(256) void k_atten(
    const float* __restrict__ AL, const float* __restrict__ REL, float* __restrict__ ATT) {
  int idx = blockIdx.x * 256 + threadIdx.x;
  if (idx >= 64*40*512) return;
  int h = idx & 511; int t2 = idx >> 9; int s = t2 % 40; int b = t2 / 40;
  const float* al = AL + b * 640 + s;
  const float* rl = REL + (size_t)b * 16 * 512 + h;
  float acc = 0.f;
#pragma unroll
  for (int r = 0; r < 16; r++) acc += al[r*40] * rl[r*512];
  ATT[idx] = acc;
}

// ================= (QT - ATT) -> bf16 split =================
__global__ __launch_bounds__(256) void k_sub(
    const float* __restrict__ QT, const float* __restrict__ ATT,
    unsigned short* __restrict__ Dhi, unsigned short* __restrict__ Dlo) {
  int idx = blockIdx.x * 256 + threadIdx.x;
  if (idx >= 64*40*512) return;
  float v = QT[idx] - ATT[idx];
  unsigned short hi = f2bf(v);
  Dhi[idx] = hi; Dlo[idx] = f2bf(v - bf2f(hi));
}

// ================= pack M2[m][c] bf16-split, with zero tail pad =================
__global__ __launch_bounds__(256) void k_m2(
    const float* __restrict__ QO2, const float* __restrict__ ATT,
    unsigned short* __restrict__ M2hi, unsigned short* __restrict__ M2lo) {
  int idx = blockIdx.x * 256 + threadIdx.x;
  if (idx >= 2626048) return;
  float v = 0.f;
  if (idx < 2621440) {
    int c = idx & 1023; int m = idx >> 10;
    v = (c < 512) ? QO2[(size_t)m*512 + c] : ATT[(size_t)m*512 + (c - 512)];
  }
  unsigned short hi = f2bf(v);
  M2hi[idx] = hi; M2lo[idx] = f2bf(v - bf2f(hi));
}

// ================= pool(bias+relu+max over l) + score =================
__global__ __launch_bounds__(256) void k_pool(
    const float* __restrict__ Y1, const float* __restrict__ Y2, const float* __restrict__ Y3,
    const float* __restrict__ b1, const float* __restrict__ b2, const float* __restrict__ b3,
    const float* __restrict__ lw, float* __restrict__ out) {
  int b = blockIdx.x, o = threadIdx.x;
  float hv = 0.f;
  if (o < 150) {
    const float* y1 = Y1 + (size_t)b*40*192 + o;
    const float* y2 = Y2 + (size_t)b*40*192 + o;
    const float* y3 = Y3 + (size_t)b*40*192 + o;
    float m1 = NEG_INF, m2 = NEG_INF, m3 = NEG_INF;
#pragma unroll 4
    for (int l = 0; l < 40; l++) m1 = fmaxf(m1, y1[l*192]);
#pragma unroll 2
    for (int l = 0; l < 38; l++) m2 = fmaxf(m2, y2[l*192]);
#pragma unroll 2
    for (int l = 0; l < 36; l++) m3 = fmaxf(m3, y3[l*192]);
    float h = fmaxf(fmaxf(m1 + b1[o], m2 + b2[o]), m3 + b3[o]);
    hv = fmaxf(h, 0.f) * lw[o];
  }
  __shared__ float sh[256];
  sh[threadIdx.x] = hv;
  __syncthreads();
  for (int st = 128; st > 0; st >>= 1) { if (threadIdx.x < st) sh[threadIdx.x] += sh[threadIdx.x+st]; __syncthreads(); }
  if (threadIdx.x == 0) out[b] = sh[0];
}

// ================= host =================
extern "C" void kernel_launch(void* const* d_in, const int* in_sizes, int n_in,
                              void* d_out, int out_size, void* d_ws, size_t ws_size,
                              hipStream_t stream) {
  const int*   q    = (const int*)d_in[0];
  const int*   wrel = (const int*)d_in[1];
  const int*   rrel = (const int*)d_in[2];
  const int*   wprv = (const int*)d_in[3];
  const int*   rprv = (const int*)d_in[4];
  const float* we   = (const float*)d_in[5];
  const float* re   = (const float*)d_in[6];
  const float* Wih_f= (const float*)d_in[7];
  const float* Whh_f= (const float*)d_in[8];
  const float* b_f  = (const float*)d_in[9];
  const float* Wih_b= (const float*)d_in[10];
  const float* Whh_b= (const float*)d_in[11];
  const float* b_b  = (const float*)d_in[12];
  const float* W    = (const float*)d_in[13];
  const float* c1w  = (const float*)d_in[14];
  const float* c1b  = (const float*)d_in[15];
  const float* c2w  = (const float*)d_in[16];
  const float* c2b  = (const float*)d_in[17];
  const float* c3w  = (const float*)d_in[18];
  const float* c3b  = (const float*)d_in[19];
  const float* lw   = (const float*)d_in[20];
  const float* l2w  = (const float*)d_in[21];
  const float* l2b  = (const float*)d_in[22];
  float* out = (float*)d_out;
  float* ws  = (float*)d_ws;

  float* WQk  = ws + OFF_WQ;
  float* B2   = ws + OFF_B2;
  unsigned short* XB3T  = (unsigned short*)(ws + OFF_XB3T);
  unsigned short* WB3T  = (unsigned short*)(ws + OFF_WB3T);
  unsigned short* L2B3T = (unsigned short*)(ws + OFF_L2B3T);
  unsigned short* C1B3T = (unsigned short*)(ws + OFF_C1B3T);
  unsigned short* C2B3T = (unsigned short*)(ws + OFF_C2B3T);
  unsigned short* C3B3T = (unsigned short*)(ws + OFF_C3B3T);
  unsigned short* Xhi   = (unsigned short*)(ws + OFF_XHI);
  unsigned short* Xlo   = (unsigned short*)(ws + OFF_XLO);
  float* XP   = ws + OFF_XP;
  float* HSQ  = ws + OFF_HSQ;
  float* HSWP = ws + OFF_HSWP;
  float* HSRP = ws + OFF_HSRP;
  float* HSWR = ws + OFF_HSWR;
  float* HSRR = ws + OFF_HSRR;
  float* CS   = ws + OFF_CS;
  float* RELP = ws + OFF_RELP;
  float* RELC = ws + OFF_RELC;
  float* RELW = ws + OFF_RELW;
  float* EN   = ws + OFF_EN;
  // XP-region aliases (XP dead after last k_step)
  float* QO1  = XP;
  float* ATT  = XP + 1310720;
  float* QO2  = XP + 2621440;
  unsigned short* Dhi  = (unsigned short*)(XP + 3932160);
  unsigned short* Dlo  = (unsigned short*)(XP + 4587520);
  unsigned short* RPhi = (unsigned short*)(XP + 5242880);
  unsigned short* RPlo = (unsigned short*)(XP + 5505024);
  unsigned short* RChi = (unsigned short*)(XP + 5767168);
  unsigned short* RClo = (unsigned short*)(XP + 6029312);
  unsigned short* M2hi = (unsigned short*)(XP + 5242880);   // overwrites RP/RC (dead by then)
  unsigned short* M2lo = (unsigned short*)(XP + 6555904);
  float* Y1   = XP + 7868928;
  float* Y2   = XP + 8360448;
  float* Y3   = XP + 8851968;

  k_prep<<<13576, 256, 0, stream>>>(Whh_f, Whh_b, b_f, b_b, Wih_f, Wih_b, W, l2w,
                                    c1w, c2w, c3w,
                                    WQk, B2, XB3T, WB3T, L2B3T, C1B3T, C2B3T, C3B3T);
  k_gather<<<NTOK, 320, 0, stream>>>(q, wrel, rrel, wprv, rprv, we, re, Xhi, Xlo);
  { dim3 g(72, 32); k_mgemm<true><<<g, 256, 0, stream>>>(Xhi, Xlo, 320, XB3T, B2, XP, 2048, 320); }

  for (int s = 0; s < 40; s++) {
    if (s < 16) { dim3 g(16, 6); k_step<4><<<g, 256, 0, stream>>>(WQk, XP, HSQ, HSWP, HSRP, HSWR, HSRR, CS, s); }
    else        { dim3 g(32, 2); k_step<2><<<g, 256, 0, stream>>>(WQk, XP, HSQ, HSWP, HSRP, HSWR, HSRR, CS, s); }
  }

  k_qo1<<<5120, 256, 0, stream>>>(HSQ, QO1);
  k_rel<<<4096, 256, 0, stream>>>(HSWP, HSRP, HSWR, HSRR, RELP, RELC, RPhi, RPlo, RChi, RClo);

  // ---- attention (previous hop) ----
  { dim3 g(16, 8); k_mgemm<false><<<g, 256, 0, stream>>>(RPhi, RPlo, 512, WB3T, nullptr, RELW, 512, 512); }
  k_energy<<<160, 256, 0, stream>>>(RELW, QO1, EN);
  k_softmax<<<64, 256, 0, stream>>>(EN);
  k_atten<<<5120, 256, 0, stream>>>(EN, RELP, ATT);
  k_sub<<<5120, 256, 0, stream>>>(QO1, ATT, Dhi, Dlo);
  { dim3 g(40, 8); k_mgemm<true><<<g, 256, 0, stream>>>(Dhi, Dlo, 512, L2B3T, l2b, QO2, 512, 512); }

  // ---- attention (current relation) ----
  { dim3 g(16, 8); k_mgemm<false><<<g, 256, 0, stream>>>(RChi, RClo, 512, WB3T, nullptr, RELW, 512, 512); }
  k_energy<<<160, 256, 0, stream>>>(RELW, QO2, EN);
  k_softmax<<<64, 256, 0, stream>>>(EN);
  k_atten<<<5120, 256, 0, stream>>>(EN, RELC, ATT);

  // ---- convs as sliding-window GEMMs over M2 (lda=1024), MFMA split ----
  k_m2<<<10258, 256, 0, stream>>>(QO2, ATT, M2hi, M2lo);
  { dim3 g(40, 3); k_mgemm<false><<<g, 256, 0, stream>>>(M2hi, M2lo, 1024, C1B3T, nullptr, Y1, 192, 1024); }
  { dim3 g(40, 3); k_mgemm<false><<<g, 256, 0, stream>>>(M2hi, M2lo, 1024, C2B3T, nullptr, Y2, 192, 3072); }
  { dim3 g(40, 3); k_mgemm<false><<<g, 256, 0, stream>>>(M2hi, M2lo, 1024, C3B3T, nullptr, Y3, 192, 5120); }
  k_pool<<<64, 256, 0, stream>>>(Y1, Y2, Y3, c1b, c2b, c3b, lw, out);
}

// Round 4
// 1046.041 us; speedup vs baseline: 2.0865x; 1.2899x over previous
//
#include <hip/hip_runtime.h>
#include <math.h>

#define NEG_INF (-3.402823466e+38f)

typedef __attribute__((ext_vector_type(8))) short short8;
typedef __attribute__((ext_vector_type(8))) unsigned short ushort8;
typedef __attribute__((ext_vector_type(4))) float f32x4;

// ---- dims ----
constexpr int NTOK = 4608;              // 2560 Q + 768 Wp + 256 Rp + 768 Wr + 256 Rr
constexpr int BH = 64 * 256;            // one (b,u) plane

// ---- ws offsets (floats); ushort arrays use 2 elems per float slot ----
constexpr size_t OFF_WQ    = 0;                          // 524288
constexpr size_t OFF_B2    = OFF_WQ    + 524288;         // 2048
constexpr size_t OFF_XB3T  = OFF_B2    + 2048;           // 2048*960 us  = 983040 fl
constexpr size_t OFF_WB3T  = OFF_XB3T  + 983040;         // 512*1536 us  = 393216 fl
constexpr size_t OFF_L2B3T = OFF_WB3T  + 393216;         // 393216 fl
constexpr size_t OFF_C1B3T = OFF_L2B3T + 393216;         // 192*3072 us  = 294912 fl
constexpr size_t OFF_C2B3T = OFF_C1B3T + 294912;         // 192*9216 us  = 884736 fl
constexpr size_t OFF_C3B3T = OFF_C2B3T + 884736;         // 192*15360 us = 1474560 fl
constexpr size_t OFF_XHI   = OFF_C3B3T + 1474560;        // 4608*320 us  = 737280 fl
constexpr size_t OFF_XLO   = OFF_XHI   + 737280;
constexpr size_t OFF_XP    = OFF_XLO   + 737280;         // 4608*2048 fp32 = 9437184
constexpr size_t OFF_HSQ   = OFF_XP    + 9437184;        // 1310720
constexpr size_t OFF_HSWP  = OFF_HSQ   + 1310720;        // 393216
constexpr size_t OFF_HSRP  = OFF_HSWP  + 393216;         // 131072
constexpr size_t OFF_HSWR  = OFF_HSRP  + 131072;         // 393216
constexpr size_t OFF_HSRR  = OFF_HSWR  + 393216;         // 131072
constexpr size_t OFF_CS    = OFF_HSRR  + 131072;         // 163840
constexpr size_t OFF_RELP  = OFF_CS    + 163840;         // 524288
constexpr size_t OFF_RELC  = OFF_RELP  + 524288;         // 524288
constexpr size_t OFF_RELW  = OFF_RELC  + 524288;         // 524288
constexpr size_t OFF_EN    = OFF_RELW  + 524288;         // 40960
// end = OFF_EN + 40960 = 19998720 floats (~80 MB)
// XP region aliases (XP dead after last k_step):
//   QO1 +0 (1310720), ATT +1310720, QO2 +2621440,
//   Dhi +3932160 (655360 fl), Dlo +4587520,
//   RPhi +5242880, RPlo +5505024, RChi +5767168, RClo +6029312 (dead before k_m2)
//   M2hi +5242880 (1313024 fl), M2lo +6555904,
//   Y1 +7868928, Y2 +8360448, Y3 +8851968 (end 9343488 < 9437184)

__device__ inline unsigned short f2bf(float f) {
  unsigned int u = __float_as_uint(f);
  u += 0x7FFFu + ((u >> 16) & 1u);          // RNE
  return (unsigned short)(u >> 16);
}
__device__ inline float bf2f(unsigned short h) {
  return __uint_as_float(((unsigned int)h) << 16);
}

// ================= prep: WQ + bias + all B3T (bf16-split, transposed, [hi|lo|hi]) ==========
__global__ __launch_bounds__(256) void k_prep(
    const float* __restrict__ Whh_f, const float* __restrict__ Whh_b,
    const float* __restrict__ b_f,   const float* __restrict__ b_b,
    const float* __restrict__ Wih_f, const float* __restrict__ Wih_b,
    const float* __restrict__ Wat,   const float* __restrict__ l2w,
    const float* __restrict__ c1w, const float* __restrict__ c2w, const float* __restrict__ c3w,
    float* __restrict__ WQ, float* __restrict__ B2,
    unsigned short* __restrict__ XB3T, unsigned short* __restrict__ WB3T,
    unsigned short* __restrict__ L2B3T,
    unsigned short* __restrict__ C1B3T, unsigned short* __restrict__ C2B3T,
    unsigned short* __restrict__ C3B3T) {
  int idx = blockIdx.x * 256 + threadIdx.x;
  if (idx < 524288) {                       // WQ[d][k4][g][u][kk]
    int d = idx >> 18, l = idx & 262143;
    int kk = l & 3, u = (l >> 2) & 255, g = (l >> 10) & 3, k4 = l >> 12;
    const float* Wh = d ? Whh_b : Whh_f;
    WQ[idx] = Wh[(size_t)(g*256 + u)*256 + k4*4 + kk];
    return;
  }
  idx -= 524288;
  if (idx < 2048) { B2[idx] = (idx < 1024) ? b_f[idx] : b_b[idx-1024]; return; }
  idx -= 2048;
  unsigned short* dst; int n, k, K;
  float w;
  if (idx < 655360) {                       // XB3T: n<2048, Kp=320 (src K=300)
    n = idx / 320; k = idx % 320; K = 320; dst = XB3T;
    w = (k < 300) ? ((n < 1024) ? Wih_f[(size_t)n*300 + k] : Wih_b[(size_t)(n-1024)*300 + k]) : 0.f;
  } else if ((idx -= 655360) < 262144) {    // WB3T: B[k][n] = Wat[k][n]
    n = idx >> 9; k = idx & 511; K = 512; dst = WB3T;
    w = Wat[(size_t)k*512 + n];
  } else if ((idx -= 262144) < 262144) {    // L2B3T: B[k][n] = l2w[n][k]
    n = idx >> 9; k = idx & 511; K = 512; dst = L2B3T;
    w = l2w[(size_t)n*512 + k];
  } else if ((idx -= 262144) < 196608) {    // C1B3T (n pad 192)
    n = idx >> 10; k = idx & 1023; K = 1024; dst = C1B3T;
    w = (n < 150) ? c1w[(size_t)n*1024 + k] : 0.f;
  } else if ((idx -= 196608) < 589824) {    // C2B3T
    n = idx / 3072; k = idx % 3072; K = 3072; dst = C2B3T;
    int kw = k >> 10, c = k & 1023;
    w = (n < 150) ? c2w[((size_t)n*1024 + c)*3 + kw] : 0.f;
  } else if ((idx -= 589824) < 983040) {    // C3B3T
    n = idx / 5120; k = idx % 5120; K = 5120; dst = C3B3T;
    int kw = k >> 10, c = k & 1023;
    w = (n < 150) ? c3w[((size_t)n*1024 + c)*5 + kw] : 0.f;
  } else return;
  unsigned short hi = f2bf(w);
  unsigned short lo = f2bf(w - bf2f(hi));
  size_t base = (size_t)n * (3*K);
  dst[base + k] = hi;
  dst[base + K + k] = lo;
  dst[base + 2*K + k] = hi;
}

// ================= gather embeddings -> bf16 split, K padded to 320 =================
__global__ __launch_bounds__(320) void k_gather(
    const int* __restrict__ q,  const int* __restrict__ wr, const int* __restrict__ rr,
    const int* __restrict__ wp, const int* __restrict__ rp,
    const float* __restrict__ we, const float* __restrict__ re,
    unsigned short* __restrict__ Xhi, unsigned short* __restrict__ Xlo) {
  int m = blockIdx.x, k = threadIdx.x;
  const float* emb; int row;
  if (m < 2560)      { int t=m>>6,    b=m&63; row = q [b*40+t]; emb = we; }
  else if (m < 3328) { int mm=m-2560; int t=mm>>6,b=mm&63; row = wp[b*12+t]; emb = we; }
  else if (m < 3584) { int mm=m-3328; int t=mm>>6,b=mm&63; row = rp[b*4 +t]; emb = re; }
  else if (m < 4352) { int mm=m-3584; int t=mm>>6,b=mm&63; row = wr[b*12+t]; emb = we; }
  else               { int mm=m-4352; int t=mm>>6,b=mm&63; row = rr[b*4 +t]; emb = re; }
  float v = (k < 300) ? emb[(size_t)row*300 + k] : 0.f;
  unsigned short hi = f2bf(v);
  Xhi[(size_t)m*320 + k] = hi;
  Xlo[(size_t)m*320 + k] = f2bf(v - bf2f(hi));
}

// ===== MFMA GEMM (bf16 3-split): C[M][N] = sum over 3K of Asel[m][kk] * Bt[n][k0] =====
template<bool BIAS>
__global__ __launch_bounds__(256) void k_mgemm(
    const unsigned short* __restrict__ Ahi, const unsigned short* __restrict__ Alo, int lda,
    const unsigned short* __restrict__ Bt, const float* __restrict__ bias,
    float* __restrict__ C, int N, int K) {
  __shared__ unsigned short As[64 * 40];   // rows padded to 40 ushorts (80 B)
  __shared__ unsigned short Bs[64 * 40];
  int tid = threadIdx.x;
  int wave = tid >> 6, lane = tid & 63;
  int quad = lane >> 4, l16 = lane & 15;
  int m0 = blockIdx.x << 6, n0 = blockIdx.y << 6;
  int K3 = 3 * K;
  int sr = tid >> 2;               // staging row 0..63
  int sc = (tid & 3) << 3;         // staging col 0,8,16,24
  f32x4 acc[4] = {};
  for (int k0 = 0; k0 < K3; k0 += 32) {
    int c = (k0 >= K) + (k0 >= 2*K);
    const unsigned short* Asrc = (c == 2) ? Alo : Ahi;
    int kk = k0 - c * K;
    ushort8 av = *(const ushort8*)(Asrc + (size_t)(m0 + sr) * lda + kk + sc);
    ushort8 bv = *(const ushort8*)(Bt + (size_t)(n0 + sr) * K3 + k0 + sc);
    *(ushort8*)&As[sr * 40 + sc] = av;
    *(ushort8*)&Bs[sr * 40 + sc] = bv;
    __syncthreads();
    short8 a  = *(const short8*)&As[(wave*16 + l16) * 40 + quad*8];
    short8 b0 = *(const short8*)&Bs[( 0 + l16) * 40 + quad*8];
    short8 b1 = *(const short8*)&Bs[(16 + l16) * 40 + quad*8];
    short8 b2 = *(const short8*)&Bs[(32 + l16) * 40 + quad*8];
    short8 b3 = *(const short8*)&Bs[(48 + l16) * 40 + quad*8];
    acc[0] = __builtin_amdgcn_mfma_f32_16x16x32_bf16(a, b0, acc[0], 0, 0, 0);
    acc[1] = __builtin_amdgcn_mfma_f32_16x16x32_bf16(a, b1, acc[1], 0, 0, 0);
    acc[2] = __builtin_amdgcn_mfma_f32_16x16x32_bf16(a, b2, acc[2], 0, 0, 0);
    acc[3] = __builtin_amdgcn_mfma_f32_16x16x32_bf16(a, b3, acc[3], 0, 0, 0);
    __syncthreads();
  }
  int row0 = m0 + wave * 16 + quad * 4;    // C/D: col=lane&15, row=quad*4+reg
#pragma unroll
  for (int t = 0; t < 4; t++) {
    int col = n0 + t * 16 + l16;
    float bb = BIAS ? bias[col] : 0.f;
#pragma unroll
    for (int r = 0; r < 4; r++)
      C[(size_t)(row0 + r) * N + col] = acc[t][r] + bb;
  }
}

// ===== fused conv GEMMs, split-K, atomic accumulate into zeroed Y =====
// blockIdx.z: [0,4) conv1 split, [4,12) conv2 split, [12,20) conv3 split
__global__ __launch_bounds__(256) void k_cgemm(
    const unsigned short* __restrict__ Ahi, const unsigned short* __restrict__ Alo,
    const unsigned short* __restrict__ B1, const unsigned short* __restrict__ B2c,
    const unsigned short* __restrict__ B3,
    float* __restrict__ Y1, float* __restrict__ Y2, float* __restrict__ Y3) {
  __shared__ unsigned short As[64 * 40];
  __shared__ unsigned short Bs[64 * 40];
  int z = blockIdx.z;
  const unsigned short* Bt; float* Y; int K, sidx, chunk;
  if (z < 4)       { Bt = B1;  Y = Y1; K = 1024; sidx = z;      chunk = 768;  }
  else if (z < 12) { Bt = B2c; Y = Y2; K = 3072; sidx = z - 4;  chunk = 1152; }
  else             { Bt = B3;  Y = Y3; K = 5120; sidx = z - 12; chunk = 1920; }
  int K3 = 3 * K;
  int ks = sidx * chunk, ke = ks + chunk;
  int tid = threadIdx.x;
  int wave = tid >> 6, lane = tid & 63;
  int quad = lane >> 4, l16 = lane & 15;
  int m0 = blockIdx.x << 6, n0 = blockIdx.y << 6;
  int sr = tid >> 2;
  int sc = (tid & 3) << 3;
  f32x4 acc[4] = {};
  for (int k0 = ks; k0 < ke; k0 += 32) {
    int c = (k0 >= K) + (k0 >= 2*K);
    const unsigned short* Asrc = (c == 2) ? Alo : Ahi;
    int kk = k0 - c * K;
    ushort8 av = *(const ushort8*)(Asrc + (size_t)(m0 + sr) * 1024 + kk + sc);
    ushort8 bv = *(const ushort8*)(Bt + (size_t)(n0 + sr) * K3 + k0 + sc);
    *(ushort8*)&As[sr * 40 + sc] = av;
    *(ushort8*)&Bs[sr * 40 + sc] = bv;
    __syncthreads();
    short8 a  = *(const short8*)&As[(wave*16 + l16) * 40 + quad*8];
    short8 b0 = *(const short8*)&Bs[( 0 + l16) * 40 + quad*8];
    short8 b1 = *(const short8*)&Bs[(16 + l16) * 40 + quad*8];
    short8 b2 = *(const short8*)&Bs[(32 + l16) * 40 + quad*8];
    short8 b3 = *(const short8*)&Bs[(48 + l16) * 40 + quad*8];
    acc[0] = __builtin_amdgcn_mfma_f32_16x16x32_bf16(a, b0, acc[0], 0, 0, 0);
    acc[1] = __builtin_amdgcn_mfma_f32_16x16x32_bf16(a, b1, acc[1], 0, 0, 0);
    acc[2] = __builtin_amdgcn_mfma_f32_16x16x32_bf16(a, b2, acc[2], 0, 0, 0);
    acc[3] = __builtin_amdgcn_mfma_f32_16x16x32_bf16(a, b3, acc[3], 0, 0, 0);
    __syncthreads();
  }
  int row0 = m0 + wave * 16 + quad * 4;
#pragma unroll
  for (int t = 0; t < 4; t++) {
    int col = n0 + t * 16 + l16;
#pragma unroll
    for (int r = 0; r < 4; r++)
      atomicAdd(&Y[(size_t)(row0 + r) * 192 + col], acc[t][r]);
  }
}

// ================= zero a float region (Y partial-sum init) =================
__global__ __launch_bounds__(256) void k_zero(float* __restrict__ p, int n4) {
  int idx = blockIdx.x * 256 + threadIdx.x;
  if (idx < n4) *(float4*)(p + (size_t)idx * 4) = make_float4(0.f, 0.f, 0.f, 0.f);
}

// ================= one recurrent step, all active (seq,dir) slots =================
template<int BB>
__global__ __launch_bounds__(256) void k_step(
    const float* __restrict__ WQ, const float* __restrict__ XP,
    float* __restrict__ hsQ, float* __restrict__ hsWp, float* __restrict__ hsRp,
    float* __restrict__ hsWr, float* __restrict__ hsRr, float* __restrict__ CS,
    int step) {
  int slot = blockIdx.y;
  int dir = slot & 1, si = slot >> 1;
  int t, T, seg; float* hs; float* cs;
  const float* ih = nullptr; const float* ic = nullptr;
  if (si == 0) { t = step; T = 40; seg = 0; hs = hsQ; cs = CS + (size_t)(0 + dir) * BH; }
  else if (step < 12) {
    t = step; T = 12;
    if (si == 1) { seg = 2560; hs = hsWp; cs = CS + (size_t)(2 + dir) * BH; }
    else         { seg = 3584; hs = hsWr; cs = CS + (size_t)(6 + dir) * BH; }
  } else {
    t = step - 12; T = 4;
    if (si == 1) { seg = 3328; hs = hsRp; cs = CS + (size_t)(4 + dir) * BH;
                   ih = hsWp + (size_t)(dir*12 + 11) * BH; ic = CS + (size_t)(2 + dir) * BH; }
    else         { seg = 4352; hs = hsRr; cs = CS + (size_t)(8 + dir) * BH;
                   ih = hsWr + (size_t)(dir*12 + 11) * BH; ic = CS + (size_t)(6 + dir) * BH; }
  }
  hs += (size_t)dir * T * BH;
  int b0 = blockIdx.x * BB;
  int u = threadIdx.x;

  __shared__ float hl[BB][260];
  for (int i = threadIdx.x; i < BB * 256; i += 256) {
    int bb = i >> 8, uu = i & 255;
    float v;
    if (t == 0) v = ih ? ih[(b0 + bb) * 256 + uu] : 0.f;
    else        v = hs[(size_t)(t-1) * BH + (b0 + bb) * 256 + uu];
    hl[bb][uu] = v;
  }
  __syncthreads();

  float acc[4][BB];
#pragma unroll
  for (int g = 0; g < 4; g++)
#pragma unroll
    for (int b = 0; b < BB; b++) acc[g][b] = 0.f;

  const float* wb = WQ + (size_t)dir * 262144 + u * 4;
#pragma unroll 2
  for (int k4 = 0; k4 < 64; k4++) {
    float4 w0 = *(const float4*)(wb + k4*4096);
    float4 w1 = *(const float4*)(wb + k4*4096 + 1024);
    float4 w2 = *(const float4*)(wb + k4*4096 + 2048);
    float4 w3 = *(const float4*)(wb + k4*4096 + 3072);
#pragma unroll
    for (int b = 0; b < BB; b++) {
      float4 h4 = *(const float4*)&hl[b][k4*4];
      acc[0][b] += w0.x*h4.x + w0.y*h4.y + w0.z*h4.z + w0.w*h4.w;
      acc[1][b] += w1.x*h4.x + w1.y*h4.y + w1.z*h4.z + w1.w*h4.w;
      acc[2][b] += w2.x*h4.x + w2.y*h4.y + w2.z*h4.z + w2.w*h4.w;
      acc[3][b] += w3.x*h4.x + w3.y*h4.y + w3.z*h4.z + w3.w*h4.w;
    }
  }

  int t_in = dir ? (T - 1 - t) : t;
#pragma unroll
  for (int b = 0; b < BB; b++) {
    const float* xr = XP + (size_t)(seg + t_in*64 + b0 + b) * 2048 + dir*1024 + u;
    float zi = acc[0][b] + xr[0];
    float zf = acc[1][b] + xr[256];
    float zg = acc[2][b] + xr[512];
    float zo = acc[3][b] + xr[768];
    float cprev;
    if (t == 0) cprev = ic ? ic[(b0 + b) * 256 + u] : 0.f;
    else        cprev = cs[(b0 + b) * 256 + u];
    float gi = 1.f / (1.f + expf(-zi));
    float gf = 1.f / (1.f + expf(-zf));
    float go = 1.f / (1.f + expf(-zo));
    float gg = tanhf(zg);
    float cn = gf * cprev + gi * gg;
    float hn = go * tanhf(cn);
    cs[(b0 + b) * 256 + u] = cn;
    hs[(size_t)t * BH + (b0 + b) * 256 + u] = hn;
  }
}

// ================= question_out as [b][s][h] =================
__global__ __launch_bounds__(256) void k_qo1(const float* __restrict__ hsQ, float* __restrict__ QT) {
  int idx = blockIdx.x * 256 + threadIdx.x;
  if (idx >= 64*40*512) return;
  int h = idx & 511; int t2 = idx >> 9; int s = t2 % 40; int b = t2 / 40;
  float v;
  if (h < 256) v = hsQ[(size_t)s * BH + b*256 + h];
  else         v = hsQ[(size_t)40 * BH + (size_t)(39 - s) * BH + b*256 + (h - 256)];
  QT[idx] = v;
}

// ================= relation tensors [b][r][h] fp32 + bf16-split, both calls ==============
__global__ __launch_bounds__(256) void k_rel(
    const float* __restrict__ hsWp, const float* __restrict__ hsRp,
    const float* __restrict__ hsWr, const float* __restrict__ hsRr,
    float* __restrict__ RELP, float* __restrict__ RELC,
    unsigned short* __restrict__ RPhi, unsigned short* __restrict__ RPlo,
    unsigned short* __restrict__ RChi, unsigned short* __restrict__ RClo) {
  int idx0 = blockIdx.x * 256 + threadIdx.x;
  if (idx0 >= 2*64*16*512) return;
  int call = idx0 >= 64*16*512;
  int idx = idx0 - call * 64*16*512;
  int h = idx & 511; int t2 = idx >> 9; int r = t2 & 15; int b = t2 >> 4;
  const float* hsW = call ? hsWr : hsWp;
  const float* hsR = call ? hsRr : hsRp;
  float v;
  if (r < 4) {
    if (h < 256) v = hsR[(size_t)r * BH + b*256 + h];
    else         v = hsR[(size_t)4 * BH + (size_t)(3 - r) * BH + b*256 + (h - 256)];
  } else {
    int t = r - 4;
    if (h < 256) v = hsW[(size_t)t * BH + b*256 + h];
    else         v = hsW[(size_t)12 * BH + (size_t)(11 - t) * BH + b*256 + (h - 256)];
  }
  unsigned short hi = f2bf(v);
  unsigned short lo = f2bf(v - bf2f(hi));
  if (call) { RELC[idx] = v; RChi[idx] = hi; RClo[idx] = lo; }
  else      { RELP[idx] = v; RPhi[idx] = hi; RPlo[idx] = lo; }
}

// ================= energy[b][r][s] =================
__global__ __launch_bounds__(256) void k_energy(
    const float* __restrict__ relW, const float* __restrict__ QT, float* __restrict__ EN) {
  int idx = blockIdx.x * 256 + threadIdx.x;
  if (idx >= 64*16*40) return;
  int s = idx % 40; int t = idx / 40; int r = t & 15; int b = t >> 4;
  const float* rw = relW + (size_t)(b*16 + r) * 512;
  const float* qv = QT   + (size_t)(b*40 + s) * 512;
  float acc = 0.f;
#pragma unroll 4
  for (int k = 0; k < 512; k += 4) {
    float4 a = *(const float4*)(rw + k);
    float4 c = *(const float4*)(qv + k);
    acc += a.x*c.x + a.y*c.y + a.z*c.z + a.w*c.w;
  }
  EN[idx] = acc;
}

// ================= softmax over 640 per b =================
__global__ __launch_bounds__(256) void k_softmax(float* __restrict__ EN) {
  int b = blockIdx.x; int tid = threadIdx.x;
  float* e = EN + b * 640;
  float v0 = e[tid] * 0.25f, v1 = e[tid + 256] * 0.25f;
  float v2 = (tid < 128) ? e[tid + 512] * 0.25f : NEG_INF;
  __shared__ float sh[256];
  sh[tid] = fmaxf(v0, fmaxf(v1, v2));
  __syncthreads();
  for (int st = 128; st > 0; st >>= 1) { if (tid < st) sh[tid] = fmaxf(sh[tid], sh[tid+st]); __syncthreads(); }
  float m = sh[0];
  __syncthreads();
  float e0 = expf(v0 - m), e1 = expf(v1 - m);
  float e2 = (tid < 128) ? expf(v2 - m) : 0.f;
  sh[tid] = e0 + e1 + e2;
  __syncthreads();
  for (int st = 128; st > 0; st >>= 1) { if (tid < st) sh[tid] += sh[tid+st]; __syncthreads(); }
  float inv = 1.f / sh[0];
  e[tid] = e0 * inv; e[tid + 256] = e1 * inv;
  if (tid < 128) e[tid + 512] = e2 * inv;
}

// ================= atten[b][s][h] =================
__global__ __launch_bounds__(256) void k_atten(
    const float* __restrict__ AL, const float* __restrict__ REL, float* __restrict__ ATT) {
  int idx = blockIdx.x * 256 + threadIdx.x;
  if (idx >= 64*40*512) return;
  int h = idx & 511; int t2 = idx >> 9; int s = t2 % 40; int b = t2 / 40;
  const float* al = AL + b * 640 + s;
  const float* rl = REL + (size_t)b * 16 * 512 + h;
  float acc = 0.f;
#pragma unroll
  for (int r = 0; r < 16; r++) acc += al[r*40] * rl[r*512];
  ATT[idx] = acc;
}

// ================= (QT - ATT) -> bf16 split =================
__global__ __launch_bounds__(256) void k_sub(
    const float* __restrict__ QT, const float* __restrict__ ATT,
    unsigned short* __restrict__ Dhi, unsigned short* __restrict__ Dlo) {
  int idx = blockIdx.x * 256 + threadIdx.x;
  if (idx >= 64*40*512) return;
  float v = QT[idx] - ATT[idx];
  unsigned short hi = f2bf(v);
  Dhi[idx] = hi; Dlo[idx] = f2bf(v - bf2f(hi));
}

// ================= pack M2[m][c] bf16-split, with zero tail pad =================
__global__ __launch_bounds__(256) void k_m2(
    const float* __restrict__ QO2, const float* __restrict__ ATT,
    unsigned short* __restrict__ M2hi, unsigned short* __restrict__ M2lo) {
  int idx = blockIdx.x * 256 + threadIdx.x;
  if (idx >= 2626048) return;
  float v = 0.f;
  if (idx < 2621440) {
    int c = idx & 1023; int m = idx >> 10;
    v = (c < 512) ? QO2[(size_t)m*512 + c] : ATT[(size_t)m*512 + (c - 512)];
  }
  unsigned short hi = f2bf(v);
  M2hi[idx] = hi; M2lo[idx] = f2bf(v - bf2f(hi));
}

// ================= pool(bias+relu+max over l) + score =================
__global__ __launch_bounds__(256) void k_pool(
    const float* __restrict__ Y1, const float* __restrict__ Y2, const float* __restrict__ Y3,
    const float* __restrict__ b1, const float* __restrict__ b2, const float* __restrict__ b3,
    const float* __restrict__ lw, float* __restrict__ out) {
  int b = blockIdx.x, o = threadIdx.x;
  float hv = 0.f;
  if (o < 150) {
    const float* y1 = Y1 + (size_t)b*40*192 + o;
    const float* y2 = Y2 + (size_t)b*40*192 + o;
    const float* y3 = Y3 + (size_t)b*40*192 + o;
    float m1 = NEG_INF, m2 = NEG_INF, m3 = NEG_INF;
#pragma unroll 4
    for (int l = 0; l < 40; l++) m1 = fmaxf(m1, y1[l*192]);
#pragma unroll 2
    for (int l = 0; l < 38; l++) m2 = fmaxf(m2, y2[l*192]);
#pragma unroll 2
    for (int l = 0; l < 36; l++) m3 = fmaxf(m3, y3[l*192]);
    float h = fmaxf(fmaxf(m1 + b1[o], m2 + b2[o]), m3 + b3[o]);
    hv = fmaxf(h, 0.f) * lw[o];
  }
  __shared__ float sh[256];
  sh[threadIdx.x] = hv;
  __syncthreads();
  for (int st = 128; st > 0; st >>= 1) { if (threadIdx.x < st) sh[threadIdx.x] += sh[threadIdx.x+st]; __syncthreads(); }
  if (threadIdx.x == 0) out[b] = sh[0];
}

// ================= host =================
extern "C" void kernel_launch(void* const* d_in, const int* in_sizes, int n_in,
                              void* d_out, int out_size, void* d_ws, size_t ws_size,
                              hipStream_t stream) {
  const int*   q    = (const int*)d_in[0];
  const int*   wrel = (const int*)d_in[1];
  const int*   rrel = (const int*)d_in[2];
  const int*   wprv = (const int*)d_in[3];
  const int*   rprv = (const int*)d_in[4];
  const float* we   = (const float*)d_in[5];
  const float* re   = (const float*)d_in[6];
  const float* Wih_f= (const float*)d_in[7];
  const float* Whh_f= (const float*)d_in[8];
  const float* b_f  = (const float*)d_in[9];
  const float* Wih_b= (const float*)d_in[10];
  const float* Whh_b= (const float*)d_in[11];
  const float* b_b  = (const float*)d_in[12];
  const float* W    = (const float*)d_in[13];
  const float* c1w  = (const float*)d_in[14];
  const float* c1b  = (const float*)d_in[15];
  const float* c2w  = (const float*)d_in[16];
  const float* c2b  = (const float*)d_in[17];
  const float* c3w  = (const float*)d_in[18];
  const float* c3b  = (const float*)d_in[19];
  const float* lw   = (const float*)d_in[20];
  const float* l2w  = (const float*)d_in[21];
  const float* l2b  = (const float*)d_in[22];
  float* out = (float*)d_out;
  float* ws  = (float*)d_ws;

  float* WQk  = ws + OFF_WQ;
  float* B2   = ws + OFF_B2;
  unsigned short* XB3T  = (unsigned short*)(ws + OFF_XB3T);
  unsigned short* WB3T  = (unsigned short*)(ws + OFF_WB3T);
  unsigned short* L2B3T = (unsigned short*)(ws + OFF_L2B3T);
  unsigned short* C1B3T = (unsigned short*)(ws + OFF_C1B3T);
  unsigned short* C2B3T = (unsigned short*)(ws + OFF_C2B3T);
  unsigned short* C3B3T = (unsigned short*)(ws + OFF_C3B3T);
  unsigned short* Xhi   = (unsigned short*)(ws + OFF_XHI);
  unsigned short* Xlo   = (unsigned short*)(ws + OFF_XLO);
  float* XP   = ws + OFF_XP;
  float* HSQ  = ws + OFF_HSQ;
  float* HSWP = ws + OFF_HSWP;
  float* HSRP = ws + OFF_HSRP;
  float* HSWR = ws + OFF_HSWR;
  float* HSRR = ws + OFF_HSRR;
  float* CS   = ws + OFF_CS;
  float* RELP = ws + OFF_RELP;
  float* RELC = ws + OFF_RELC;
  float* RELW = ws + OFF_RELW;
  float* EN   = ws + OFF_EN;
  // XP-region aliases (XP dead after last k_step)
  float* QO1  = XP;
  float* ATT  = XP + 1310720;
  float* QO2  = XP + 2621440;
  unsigned short* Dhi  = (unsigned short*)(XP + 3932160);
  unsigned short* Dlo  = (unsigned short*)(XP + 4587520);
  unsigned short* RPhi = (unsigned short*)(XP + 5242880);
  unsigned short* RPlo = (unsigned short*)(XP + 5505024);
  unsigned short* RChi = (unsigned short*)(XP + 5767168);
  unsigned short* RClo = (unsigned short*)(XP + 6029312);
  unsigned short* M2hi = (unsigned short*)(XP + 5242880);   // overwrites RP/RC (dead by then)
  unsigned short* M2lo = (unsigned short*)(XP + 6555904);
  float* Y1   = XP + 7868928;
  float* Y2   = XP + 8360448;
  float* Y3   = XP + 8851968;

  k_prep<<<13576, 256, 0, stream>>>(Whh_f, Whh_b, b_f, b_b, Wih_f, Wih_b, W, l2w,
                                    c1w, c2w, c3w,
                                    WQk, B2, XB3T, WB3T, L2B3T, C1B3T, C2B3T, C3B3T);
  k_gather<<<NTOK, 320, 0, stream>>>(q, wrel, rrel, wprv, rprv, we, re, Xhi, Xlo);
  { dim3 g(72, 32); k_mgemm<true><<<g, 256, 0, stream>>>(Xhi, Xlo, 320, XB3T, B2, XP, 2048, 320); }

  for (int s = 0; s < 40; s++) {
    if (s < 16) { dim3 g(16, 6); k_step<4><<<g, 256, 0, stream>>>(WQk, XP, HSQ, HSWP, HSRP, HSWR, HSRR, CS, s); }
    else        { dim3 g(32, 2); k_step<2><<<g, 256, 0, stream>>>(WQk, XP, HSQ, HSWP, HSRP, HSWR, HSRR, CS, s); }
  }

  k_qo1<<<5120, 256, 0, stream>>>(HSQ, QO1);
  k_rel<<<4096, 256, 0, stream>>>(HSWP, HSRP, HSWR, HSRR, RELP, RELC, RPhi, RPlo, RChi, RClo);

  // ---- attention (previous hop) ----
  { dim3 g(16, 8); k_mgemm<false><<<g, 256, 0, stream>>>(RPhi, RPlo, 512, WB3T, nullptr, RELW, 512, 512); }
  k_energy<<<160, 256, 0, stream>>>(RELW, QO1, EN);
  k_softmax<<<64, 256, 0, stream>>>(EN);
  k_atten<<<5120, 256, 0, stream>>>(EN, RELP, ATT);
  k_sub<<<5120, 256, 0, stream>>>(QO1, ATT, Dhi, Dlo);
  { dim3 g(40, 8); k_mgemm<true><<<g, 256, 0, stream>>>(Dhi, Dlo, 512, L2B3T, l2b, QO2, 512, 512); }

  // ---- attention (current relation) ----
  { dim3 g(16, 8); k_mgemm<false><<<g, 256, 0, stream>>>(RChi, RClo, 512, WB3T, nullptr, RELW, 512, 512); }
  k_energy<<<160, 256, 0, stream>>>(RELW, QO2, EN);
  k_softmax<<<64, 256, 0, stream>>>(EN);
  k_atten<<<5120, 256, 0, stream>>>(EN, RELC, ATT);

  // ---- convs: fused split-K MFMA GEMM, atomic accumulate into zeroed Y ----
  k_m2<<<10258, 256, 0, stream>>>(QO2, ATT, M2hi, M2lo);
  k_zero<<<1440, 256, 0, stream>>>(Y1, 368640);   // zero Y1..Y3 (contiguous 1474560 fl)
  { dim3 g(40, 3, 20); k_cgemm<<<g, 256, 0, stream>>>(M2hi, M2lo, C1B3T, C2B3T, C3B3T, Y1, Y2, Y3); }
  k_pool<<<64, 256, 0, stream>>>(Y1, Y2, Y3, c1b, c2b, c3b, lw, out);
}